// Round 7
// baseline (144.834 us; speedup 1.0000x reference)
//
#include <hip/hip_runtime.h>
#include <hip/hip_bf16.h>

#define B 8
#define T 1024
#define E 128
#define H 8
#define DH 16
#define E3 384

typedef __attribute__((ext_vector_type(8))) short short8;
typedef __attribute__((ext_vector_type(4))) short short4s;
typedef __attribute__((ext_vector_type(4))) float f32x4;

// fp32 -> bf16 (round-to-nearest-even), bit pattern in a short
static __device__ inline short bf16s(float x) {
    union { float f; unsigned u; } v; v.f = x;
    unsigned r = v.u + 0x7fffu + ((v.u >> 16) & 1u);
    return (short)(r >> 16);
}

// exp2 via the HW transcendental (1 inst)
#if __has_builtin(__builtin_amdgcn_exp2f)
static __device__ inline float fexp2(float x) { return __builtin_amdgcn_exp2f(x); }
#else
static __device__ inline float fexp2(float x) { return __builtin_exp2f(x); }
#endif

// pack two fp32 into bf16x2 via v_cvt_pk_bf16_f32
static __device__ inline __hip_bfloat162 pk2(float a, float b) {
    float2 t; t.x = a; t.y = b;
    return __float22bfloat162_rn(t);
}

// async global->LDS, 16B per lane: LDS gets lane l's data at base + l*16
static __device__ inline void stage16(const void* g, void* l) {
    __builtin_amdgcn_global_load_lds(
        (const __attribute__((address_space(1))) void*)g,
        (__attribute__((address_space(3))) void*)l,
        16, 0, 0);
}

#define QSCALE 0.36067376022224085f   /* 0.25 * log2(e) */

// ---------------------------------------------------------------------------
// Kernel 1: pack win into bf16 K=256 complex-packed layout (precedes qkv).
// ---------------------------------------------------------------------------
__global__ void pack_win_kernel(
    const float* __restrict__ win_re, const float* __restrict__ win_im,
    short* __restrict__ Wp_re, short* __restrict__ Wp_im)
{
    int idx = blockIdx.x * 256 + threadIdx.x;   // [0, 384*128)
    int j = idx >> 7, e = idx & 127;
    float wr = win_re[idx], wi = win_im[idx];
    Wp_re[j*256 + e]       = bf16s(wr);
    Wp_re[j*256 + 128 + e] = bf16s(-wi);
    Wp_im[j*256 + e]       = bf16s(wi);
    Wp_im[j*256 + 128 + e] = bf16s(wr);
}

// ---------------------------------------------------------------------------
// Kernel 2: QKV projection + piggy-backed fuse-weights blocks.
// Round-7 change: xf fragments are wave-INDEPENDENT (lane-only), yet each of
// the 4 waves was loading+converting them redundantly (64 scalar loads + 32
// cvt_pk per thread). Now wave w builds kt = {2w, 2w+1}, publishes to LDS
// [kt][lane] (lane*16B, the same conflict-benign pattern attn uses), one
// barrier, all waves ds_read_b128 all 8. Bit-identical fragment values;
// global X traffic 32MB -> 8MB; conversion VALU / 4.
//   blocks [0,512):   qkv t-tiles
//   blocks [512,576): Wfp fuse (idx = (bid-512)*256 + tid)
//   block  576:       fused bias (threads 0..127)
// ---------------------------------------------------------------------------
__global__ __launch_bounds__(256) void qkv_fuse_kernel(
    const float* __restrict__ x_re, const float* __restrict__ x_im,
    const short* __restrict__ Wp_re, const short* __restrict__ Wp_im,
    const float* __restrict__ bin_re, const float* __restrict__ bin_im,
    const float* __restrict__ wout_re, const float* __restrict__ wout_im,
    const float* __restrict__ bout_re, const float* __restrict__ bout_im,
    const float* __restrict__ wt_re,   const float* __restrict__ wt_im,
    const float* __restrict__ bt_re,   const float* __restrict__ bt_im,
    short* __restrict__ Qpk, short* __restrict__ Kpk,
    short* __restrict__ Vtre, short* __restrict__ Vtim,
    short* __restrict__ Wfp_re, short* __restrict__ Wfp_im,
    float* __restrict__ bf_re, float* __restrict__ bf_im)
{
    __shared__ short8 xsh[8][64];      // 8 KB: [kt][lane]

    int bid = blockIdx.x;
    int tid = threadIdx.x;

    if (bid < 512) {
        // ---- qkv ----
        int wave = tid >> 6, lane = tid & 63;
        int col  = lane & 15, quad = lane >> 4;
        int ttile = bid;
        int b  = ttile >> 6;
        int tb = (ttile & 63) * 16 + col;

        // wave w builds fragments kt = 2w, 2w+1 and shares via LDS
        #pragma unroll
        for (int t = 0; t < 2; ++t) {
            int kt = wave * 2 + t;
            const float* xs = (kt < 4) ? x_re : x_im;
            const float* p = &xs[((long)(b*E + (kt & 3)*32 + quad*8))*T + tb];
            float v0 = p[0], v1 = p[(long)T], v2 = p[2L*T], v3 = p[3L*T];
            float v4 = p[4L*T], v5 = p[5L*T], v6 = p[6L*T], v7 = p[7L*T];
            short8 xv;
            __hip_bfloat162* xp = (__hip_bfloat162*)&xv;
            xp[0] = pk2(v0, v1); xp[1] = pk2(v2, v3);
            xp[2] = pk2(v4, v5); xp[3] = pk2(v6, v7);
            xsh[kt][lane] = xv;
        }
        __syncthreads();

        short8 xf[8];
        #pragma unroll
        for (int kt = 0; kt < 8; ++kt) xf[kt] = xsh[kt][lane];

        const f32x4 zero = {0.f,0.f,0.f,0.f};

        #pragma unroll
        for (int half = 0; half < 2; ++half) {
            const short* Wsel = half ? Wp_im : Wp_re;
            const float* bias = half ? bin_im : bin_re;

            for (int ni = 0; ni < 6; ++ni) {
                int jt = wave * 6 + ni;            // [0,24): which*8 + h
                const short* wrow = &Wsel[(jt*16 + col)*256 + quad*8];
                f32x4 acc = zero;
                #pragma unroll
                for (int kt = 0; kt < 8; ++kt) {
                    short8 af = *(const short8*)(wrow + kt*32);
                    acc = __builtin_amdgcn_mfma_f32_16x16x32_bf16(af, xf[kt], acc, 0, 0, 0);
                }
                int which = jt >> 3;               // 0 q, 1 k, 2 v
                int h = jt & 7;
                float scale = (which == 0) ? QSCALE : 1.0f;
                f32x4 res;
                #pragma unroll
                for (int r = 0; r < 4; ++r) {
                    int jg = which*128 + h*16 + quad*4 + r;
                    res[r] = (acc[r] + bias[jg]) * scale;
                }
                long bh = b*H + h;
                if (which == 2) {
                    // V transposed + pi-interleaved: Vt[bh][dh][blk*32 + pos]
                    short* vt = half ? Vtim : Vtre;
                    int tloc = tb & 31, tblk = tb & ~31;
                    int u  = tloc & 15;
                    int kk = (u >> 2)*8 + (u & 3) + ((tloc >= 16) ? 4 : 0);
                    #pragma unroll
                    for (int r = 0; r < 4; ++r)
                        vt[(bh*DH + quad*4 + r)*T + tblk + kk] = bf16s(res[r]);
                } else {
                    short* qk = (which == 0) ? Qpk : Kpk;
                    short4s pk;
                    __hip_bfloat162* pp = (__hip_bfloat162*)&pk;
                    pp[0] = pk2(res[0], res[1]);
                    pp[1] = pk2(res[2], res[3]);
                    *(short4s*)&qk[(bh*T + tb)*32 + half*16 + quad*4] = pk;
                }
            }
        }
    } else if (bid < 576) {
        // ---- fuse output linears: wf = wt @ wout (complex) ----
        int idx = (bid - 512) * 256 + tid;        // [0, E*E)
        int j = idx >> 7, e = idx & 127;
        float ar = 0.f, ai = 0.f;
        for (int m = 0; m < E; ++m) {
            float tr = wt_re[j*E+m], ti = wt_im[j*E+m];
            float pr = wout_re[m*E+e], pi = wout_im[m*E+e];
            ar += tr*pr - ti*pi;
            ai += tr*pi + ti*pr;
        }
        Wfp_re[j*256 + e]       = bf16s(ar);
        Wfp_re[j*256 + 128 + e] = bf16s(-ai);
        Wfp_im[j*256 + e]       = bf16s(ai);
        Wfp_im[j*256 + 128 + e] = bf16s(ar);
    } else {
        // ---- fused bias: bf = wt @ bout + bt ----
        if (tid < E) {
            float br = bt_re[tid], bi = bt_im[tid];
            for (int m = 0; m < E; ++m) {
                float tr = wt_re[tid*E+m], ti = wt_im[tid*E+m];
                br += tr*bout_re[m] - ti*bout_im[m];
                bi += tr*bout_im[m] + ti*bout_re[m];
            }
            bf_re[tid] = br; bf_im[tid] = bi;
        }
    }
}

// ---------------------------------------------------------------------------
// Kernel 3: MFMA flash attention with LDS-shared K/V (round-6 verified).
// The 4 components (kf0,kf1,vr,vi -- identical across waves) are staged ONCE
// per block: wave w issues one global_load_lds for component w; LDS holds
// lane l's data at l*16, read back at l*16 -> bit-identical fragments.
// Double-buffered 8KB LDS, one __syncthreads per tile. Loads/block-iter: 4.
// ---------------------------------------------------------------------------
__global__ __launch_bounds__(256, 2) void attn_mfma_kernel(
    const short* __restrict__ Qpk, const short* __restrict__ Kpk,
    const short* __restrict__ Vtre, const short* __restrict__ Vtim,
    short* __restrict__ Opk)
{
    __shared__ short lbuf[2][4][512];   // [parity][component][1KB]

    int id   = blockIdx.x;
    int bh   = id & 63;
    int q0   = (id >> 6) * 128;
    int tid  = threadIdx.x;
    int wave = tid >> 6;
    int lane = tid & 63;
    int col  = lane & 15;
    int quad = lane >> 4;

    long kq_base = (long)bh * T * 32;
    int qbase = q0 + wave * 32;

    short8 qfA = *(const short8*)&Qpk[kq_base + (long)(qbase + col)*32 + quad*8];
    short8 qfB = *(const short8*)&Qpk[kq_base + (long)(qbase + 16 + col)*32 + quad*8];

    // this wave's staging component: 0=kf0, 1=kf1, 2=vr, 3=vi
    const short* gsrc;
    int gstep;
    if (wave == 0)      { gsrc = &Kpk[kq_base + col*32 + quad*8];              gstep = 1024; }
    else if (wave == 1) { gsrc = &Kpk[kq_base + 512 + col*32 + quad*8];        gstep = 1024; }
    else if (wave == 2) { gsrc = &Vtre[(long)bh*DH*T + (long)col*T + quad*8];  gstep = 32; }
    else                { gsrc = &Vtim[(long)bh*DH*T + (long)col*T + quad*8];  gstep = 32; }

    short8 ones;
    #pragma unroll
    for (int i = 0; i < 8; ++i) ones[i] = (short)0x3F80;   // bf16 1.0

    f32x4 oAr = {0,0,0,0}, oAi = {0,0,0,0}, lA = {0,0,0,0};
    f32x4 oBr = {0,0,0,0}, oBi = {0,0,0,0}, lB = {0,0,0,0};
    const f32x4 zero = {0.f,0.f,0.f,0.f};

    // prologue: stage tile 0 into parity 0
    stage16(gsrc, &lbuf[0][wave][0]);
    gsrc += gstep;
    __syncthreads();                    // tile 0 in LDS (vmcnt drained)

    for (int i = 0; i < 32; ++i) {
        int p = i & 1;
        // stage tile i+1 into the other buffer (overwrites tile i-1, whose
        // reads completed before the previous barrier). Tile-32 over-read
        // lands in LDS unused -- global side stays inside the workspace.
        stage16(gsrc, &lbuf[p^1][wave][0]);
        gsrc += gstep;

        // fragments from LDS (bit-identical to the original global loads)
        short8 kf0 = *(const short8*)&lbuf[p][0][lane*8];
        short8 kf1 = *(const short8*)&lbuf[p][1][lane*8];
        short8 vr  = *(const short8*)&lbuf[p][2][lane*8];
        short8 vi  = *(const short8*)&lbuf[p][3][lane*8];

        __builtin_amdgcn_s_setprio(1);
        f32x4 sA0 = __builtin_amdgcn_mfma_f32_16x16x32_bf16(kf0, qfA, zero, 0, 0, 0);
        f32x4 sA1 = __builtin_amdgcn_mfma_f32_16x16x32_bf16(kf1, qfA, zero, 0, 0, 0);
        f32x4 sB0 = __builtin_amdgcn_mfma_f32_16x16x32_bf16(kf0, qfB, zero, 0, 0, 0);
        f32x4 sB1 = __builtin_amdgcn_mfma_f32_16x16x32_bf16(kf1, qfB, zero, 0, 0, 0);
        __builtin_amdgcn_s_setprio(0);

        short8 pfA, pfB;
        {
            __hip_bfloat162* pa = (__hip_bfloat162*)&pfA;
            pa[0] = pk2(fexp2(sA0[0]), fexp2(sA0[1]));
            pa[1] = pk2(fexp2(sA0[2]), fexp2(sA0[3]));
            pa[2] = pk2(fexp2(sA1[0]), fexp2(sA1[1]));
            pa[3] = pk2(fexp2(sA1[2]), fexp2(sA1[3]));
            __hip_bfloat162* pb = (__hip_bfloat162*)&pfB;
            pb[0] = pk2(fexp2(sB0[0]), fexp2(sB0[1]));
            pb[1] = pk2(fexp2(sB0[2]), fexp2(sB0[3]));
            pb[2] = pk2(fexp2(sB1[0]), fexp2(sB1[1]));
            pb[3] = pk2(fexp2(sB1[2]), fexp2(sB1[3]));
        }

        __builtin_amdgcn_s_setprio(1);
        oAr = __builtin_amdgcn_mfma_f32_16x16x32_bf16(vr, pfA, oAr, 0, 0, 0);
        oAi = __builtin_amdgcn_mfma_f32_16x16x32_bf16(vi, pfA, oAi, 0, 0, 0);
        lA  = __builtin_amdgcn_mfma_f32_16x16x32_bf16(ones, pfA, lA, 0, 0, 0);
        oBr = __builtin_amdgcn_mfma_f32_16x16x32_bf16(vr, pfB, oBr, 0, 0, 0);
        oBi = __builtin_amdgcn_mfma_f32_16x16x32_bf16(vi, pfB, oBi, 0, 0, 0);
        lB  = __builtin_amdgcn_mfma_f32_16x16x32_bf16(ones, pfB, lB, 0, 0, 0);
        __builtin_amdgcn_s_setprio(0);

        __syncthreads();   // drains this iter's stage; syncs buf reads
    }

    int b = bh >> 3, h = bh & 7;
    float invA = 1.0f / lA[0];
    float invB = 1.0f / lB[0];

    long orowA = ((long)(b*T + qbase + col))*256 + h*16 + quad*4;
    {
        short4s pr, pi_;
        __hip_bfloat162* a = (__hip_bfloat162*)&pr;
        a[0] = pk2(oAr[0]*invA, oAr[1]*invA);
        a[1] = pk2(oAr[2]*invA, oAr[3]*invA);
        __hip_bfloat162* c = (__hip_bfloat162*)&pi_;
        c[0] = pk2(oAi[0]*invA, oAi[1]*invA);
        c[1] = pk2(oAi[2]*invA, oAi[3]*invA);
        *(short4s*)&Opk[orowA]       = pr;
        *(short4s*)&Opk[orowA + 128] = pi_;
    }
    long orowB = orowA + 16L*256;
    {
        short4s pr, pi_;
        __hip_bfloat162* a = (__hip_bfloat162*)&pr;
        a[0] = pk2(oBr[0]*invB, oBr[1]*invB);
        a[1] = pk2(oBr[2]*invB, oBr[3]*invB);
        __hip_bfloat162* c = (__hip_bfloat162*)&pi_;
        c[0] = pk2(oBi[0]*invB, oBi[1]*invB);
        c[1] = pk2(oBi[2]*invB, oBi[3]*invB);
        *(short4s*)&Opk[orowB]       = pr;
        *(short4s*)&Opk[orowB + 128] = pi_;
    }
}

// ---------------------------------------------------------------------------
// Kernel 4: MFMA output projection. Round-7 change: the xf row-fragments are
// wave-independent; stage them once per block via LDS (wave w loads kt pair
// {2w,2w+1}) instead of 4x redundant global reads. Bit-identical values.
// ---------------------------------------------------------------------------
__global__ __launch_bounds__(256) void outproj_mfma_kernel(
    const short* __restrict__ Opk,
    const short* __restrict__ Wfp_re, const short* __restrict__ Wfp_im,
    const float* __restrict__ bf_re, const float* __restrict__ bf_im,
    float* __restrict__ out)
{
    __shared__ short8 osh[8][64];      // 8 KB: [kt][lane]

    int tid  = threadIdx.x;
    int wave = tid >> 6, lane = tid & 63;
    int col  = lane & 15, quad = lane >> 4;
    int ttile = blockIdx.x;            // [0,512)
    int b  = ttile >> 6;
    int tb = (ttile & 63) * 16 + col;
    long trow = (long)b*T + tb;

    #pragma unroll
    for (int t = 0; t < 2; ++t) {
        int kt = wave * 2 + t;
        osh[kt][lane] = *(const short8*)&Opk[trow*256 + kt*32 + quad*8];
    }
    __syncthreads();

    short8 xf[8];
    #pragma unroll
    for (int kt = 0; kt < 8; ++kt) xf[kt] = osh[kt][lane];

    const f32x4 zero = {0.f,0.f,0.f,0.f};
    #pragma unroll
    for (int ni = 0; ni < 4; ++ni) {
        int nt = wave * 4 + ni;            // [0,16)
        int is_im = nt >= 8;
        int jt = is_im ? nt - 8 : nt;      // [0,8)
        const short* Wsel = is_im ? Wfp_im : Wfp_re;
        const short* wrow = &Wsel[(jt*16 + col)*256 + quad*8];
        f32x4 acc = zero;
        #pragma unroll
        for (int kt = 0; kt < 8; ++kt) {
            short8 af = *(const short8*)(wrow + kt*32);
            acc = __builtin_amdgcn_mfma_f32_16x16x32_bf16(af, xf[kt], acc, 0, 0, 0);
        }
        const float* bias = is_im ? bf_im : bf_re;
        long part = is_im ? (long)B*E*T : 0;
        #pragma unroll
        for (int r = 0; r < 4; ++r) {
            int j = jt*16 + quad*4 + r;
            out[part + ((long)(b*E + j))*T + tb] = acc[r] + bias[j];
        }
    }
}

// ---------------------------------------------------------------------------
extern "C" void kernel_launch(void* const* d_in, const int* in_sizes, int n_in,
                              void* d_out, int out_size, void* d_ws, size_t ws_size,
                              hipStream_t stream)
{
    const float* x_re    = (const float*)d_in[0];
    const float* x_im    = (const float*)d_in[1];
    const float* win_re  = (const float*)d_in[2];
    const float* win_im  = (const float*)d_in[3];
    const float* bin_re  = (const float*)d_in[4];
    const float* bin_im  = (const float*)d_in[5];
    const float* wout_re = (const float*)d_in[6];
    const float* wout_im = (const float*)d_in[7];
    const float* bout_re = (const float*)d_in[8];
    const float* bout_im = (const float*)d_in[9];
    const float* wt_re   = (const float*)d_in[10];
    const float* wt_im   = (const float*)d_in[11];
    const float* bt_re   = (const float*)d_in[12];
    const float* bt_im   = (const float*)d_in[13];
    float* out = (float*)d_out;

    // workspace layout (shorts/floats)
    short* Qpk  = (short*)d_ws;                       // 64*1024*32 = 2M shorts
    short* Kpk  = Qpk + (long)B*H*T*32;
    short* Vtre = Kpk + (long)B*H*T*32;               // 64*16*1024 = 1M shorts
    short* Vtim = Vtre + (long)B*H*DH*T;
    short* Opk  = Vtim + (long)B*H*DH*T;              // 8*1024*256 = 2M shorts
    short* Wp_re  = Opk + (long)B*T*256;
    short* Wp_im  = Wp_re + E3*256;
    short* Wfp_re = Wp_im + E3*256;
    short* Wfp_im = Wfp_re + E*256;
    float* bf_re  = (float*)(Wfp_im + E*256);
    float* bf_im  = bf_re + E;

    pack_win_kernel<<<dim3(E3*E/256), dim3(256), 0, stream>>>(
        win_re, win_im, Wp_re, Wp_im);

    qkv_fuse_kernel<<<dim3(577), dim3(256), 0, stream>>>(
        x_re, x_im, Wp_re, Wp_im, bin_re, bin_im,
        wout_re, wout_im, bout_re, bout_im,
        wt_re, wt_im, bt_re, bt_im,
        Qpk, Kpk, Vtre, Vtim,
        Wfp_re, Wfp_im, bf_re, bf_im);

    attn_mfma_kernel<<<dim3(8 * 64), dim3(256), 0, stream>>>(
        Qpk, Kpk, Vtre, Vtim, Opk);

    outproj_mfma_kernel<<<dim3(512), dim3(256), 0, stream>>>(
        Opk, Wfp_re, Wfp_im, bf_re, bf_im, out);
}

// Round 8
// 137.712 us; speedup vs baseline: 1.0517x; 1.0517x over previous
//
#include <hip/hip_runtime.h>
#include <hip/hip_bf16.h>

#define B 8
#define T 1024
#define E 128
#define H 8
#define DH 16
#define E3 384

typedef __attribute__((ext_vector_type(8))) short short8;
typedef __attribute__((ext_vector_type(4))) short short4s;
typedef __attribute__((ext_vector_type(4))) float f32x4;

// fp32 -> bf16 (round-to-nearest-even), bit pattern in a short
static __device__ inline short bf16s(float x) {
    union { float f; unsigned u; } v; v.f = x;
    unsigned r = v.u + 0x7fffu + ((v.u >> 16) & 1u);
    return (short)(r >> 16);
}

// exp2 via the HW transcendental (1 inst)
#if __has_builtin(__builtin_amdgcn_exp2f)
static __device__ inline float fexp2(float x) { return __builtin_amdgcn_exp2f(x); }
#else
static __device__ inline float fexp2(float x) { return __builtin_exp2f(x); }
#endif

// pack two fp32 into bf16x2 via v_cvt_pk_bf16_f32
static __device__ inline __hip_bfloat162 pk2(float a, float b) {
    float2 t; t.x = a; t.y = b;
    return __float22bfloat162_rn(t);
}

// async global->LDS, 16B per lane: LDS gets lane l's data at base + l*16
static __device__ inline void stage16(const void* g, void* l) {
    __builtin_amdgcn_global_load_lds(
        (const __attribute__((address_space(1))) void*)g,
        (__attribute__((address_space(3))) void*)l,
        16, 0, 0);
}

#define QSCALE 0.36067376022224085f   /* 0.25 * log2(e) */

// ---------------------------------------------------------------------------
// Kernel 1: pack win into bf16 K=256 complex-packed layout (precedes qkv).
// ---------------------------------------------------------------------------
__global__ void pack_win_kernel(
    const float* __restrict__ win_re, const float* __restrict__ win_im,
    short* __restrict__ Wp_re, short* __restrict__ Wp_im)
{
    int idx = blockIdx.x * 256 + threadIdx.x;   // [0, 384*128)
    int j = idx >> 7, e = idx & 127;
    float wr = win_re[idx], wi = win_im[idx];
    Wp_re[j*256 + e]       = bf16s(wr);
    Wp_re[j*256 + 128 + e] = bf16s(-wi);
    Wp_im[j*256 + e]       = bf16s(wi);
    Wp_im[j*256 + 128 + e] = bf16s(wr);
}

// ---------------------------------------------------------------------------
// Kernel 2: QKV projection, register-blocked over t + piggy-backed fuse.
// Round-8 change: the old 16-t blocks each streamed the ENTIRE 384KB Wp
// from L2 (512 x 384KB = 196MB) at a 1:1 W-load:MFMA ratio. New shape:
// grid = 128 t-tiles (64 t) x 4 j-groups. Per block: stage 64x256 X
// fragments to 32KB LDS once (wave w builds t-subtile w), copy to regs
// (xr[4][8], fully unrolled -> 128 VGPR), then each j-unit's 8 af loads
// feed 32 MFMAs (4 t-subtiles). W traffic /4, load:MFMA ratio /4.
// Per-output arithmetic bit-identical (same pk2 bits, same kt order,
// same store formulas with tb = t0 + ts*16 + col).
//   blocks [0,512):   qkv (jg = bid&3, ttile = bid>>2)
//   blocks [512,576): Wfp fuse (idx = (bid-512)*256 + tid)
//   block  576:       fused bias (threads 0..127)
// ---------------------------------------------------------------------------
__global__ __launch_bounds__(256, 2) void qkv_fuse_kernel(
    const float* __restrict__ x_re, const float* __restrict__ x_im,
    const short* __restrict__ Wp_re, const short* __restrict__ Wp_im,
    const float* __restrict__ bin_re, const float* __restrict__ bin_im,
    const float* __restrict__ wout_re, const float* __restrict__ wout_im,
    const float* __restrict__ bout_re, const float* __restrict__ bout_im,
    const float* __restrict__ wt_re,   const float* __restrict__ wt_im,
    const float* __restrict__ bt_re,   const float* __restrict__ bt_im,
    short* __restrict__ Qpk, short* __restrict__ Kpk,
    short* __restrict__ Vtre, short* __restrict__ Vtim,
    short* __restrict__ Wfp_re, short* __restrict__ Wfp_im,
    float* __restrict__ bf_re, float* __restrict__ bf_im)
{
    __shared__ short8 xsh[4][8][64];   // 32 KB: [tsub][kt][lane]

    int bid = blockIdx.x;
    int tid = threadIdx.x;

    if (bid < 512) {
        // ---- qkv ----
        int wave = tid >> 6, lane = tid & 63;
        int col  = lane & 15, quad = lane >> 4;
        int jg    = bid & 3;           // j-group: 6 j-tiles
        int ttile = bid >> 2;          // [0,128): 64-t tile
        int b  = ttile >> 4;
        int t0 = (ttile & 15) * 64;

        // wave w builds t-subtile w's 8 kt-fragments, shares via LDS
        {
            int tglob = t0 + wave*16 + col;
            #pragma unroll
            for (int kt = 0; kt < 8; ++kt) {
                const float* xs = (kt < 4) ? x_re : x_im;
                const float* p = &xs[((long)(b*E + (kt & 3)*32 + quad*8))*T + tglob];
                float v0 = p[0], v1 = p[(long)T], v2 = p[2L*T], v3 = p[3L*T];
                float v4 = p[4L*T], v5 = p[5L*T], v6 = p[6L*T], v7 = p[7L*T];
                short8 xv;
                __hip_bfloat162* xp = (__hip_bfloat162*)&xv;
                xp[0] = pk2(v0, v1); xp[1] = pk2(v2, v3);
                xp[2] = pk2(v4, v5); xp[3] = pk2(v6, v7);
                xsh[wave][kt][lane] = xv;
            }
        }
        __syncthreads();

        // all 4 t-subtiles' fragments into registers (static indexing)
        short8 xr[4][8];
        #pragma unroll
        for (int ts = 0; ts < 4; ++ts)
            #pragma unroll
            for (int kt = 0; kt < 8; ++kt)
                xr[ts][kt] = xsh[ts][kt][lane];

        const f32x4 zero = {0.f,0.f,0.f,0.f};

        // 12 j-units (6 j-tiles x 2 halves) / 4 waves = 3 per wave
        for (int ui = 0; ui < 3; ++ui) {
            int idx  = wave * 3 + ui;          // [0,12)
            int half = idx >= 6;
            int u    = half ? idx - 6 : idx;
            int jt   = jg * 6 + u;             // [0,24): which*8 + h
            const short* Wsel = half ? Wp_im : Wp_re;
            const float* bias = half ? bin_im : bin_re;
            const short* wrow = &Wsel[(jt*16 + col)*256 + quad*8];

            f32x4 acc[4] = {zero, zero, zero, zero};
            #pragma unroll
            for (int kt = 0; kt < 8; ++kt) {
                short8 af = *(const short8*)(wrow + kt*32);
                #pragma unroll
                for (int ts = 0; ts < 4; ++ts)
                    acc[ts] = __builtin_amdgcn_mfma_f32_16x16x32_bf16(af, xr[ts][kt], acc[ts], 0, 0, 0);
            }

            int which = jt >> 3;               // 0 q, 1 k, 2 v
            int h = jt & 7;
            float scale = (which == 0) ? QSCALE : 1.0f;
            long bh = b*H + h;

            #pragma unroll
            for (int ts = 0; ts < 4; ++ts) {
                int tb = t0 + ts*16 + col;
                f32x4 res;
                #pragma unroll
                for (int r = 0; r < 4; ++r) {
                    int jgl = which*128 + h*16 + quad*4 + r;
                    res[r] = (acc[ts][r] + bias[jgl]) * scale;
                }
                if (which == 2) {
                    // V transposed + pi-interleaved: Vt[bh][dh][blk*32 + pos]
                    short* vt = half ? Vtim : Vtre;
                    int tloc = tb & 31, tblk = tb & ~31;
                    int u2 = tloc & 15;
                    int kk = (u2 >> 2)*8 + (u2 & 3) + ((tloc >= 16) ? 4 : 0);
                    #pragma unroll
                    for (int r = 0; r < 4; ++r)
                        vt[(bh*DH + quad*4 + r)*T + tblk + kk] = bf16s(res[r]);
                } else {
                    short* qk = (which == 0) ? Qpk : Kpk;
                    short4s pk;
                    __hip_bfloat162* pp = (__hip_bfloat162*)&pk;
                    pp[0] = pk2(res[0], res[1]);
                    pp[1] = pk2(res[2], res[3]);
                    *(short4s*)&qk[(bh*T + tb)*32 + half*16 + quad*4] = pk;
                }
            }
        }
    } else if (bid < 576) {
        // ---- fuse output linears: wf = wt @ wout (complex) ----
        int idx = (bid - 512) * 256 + tid;        // [0, E*E)
        int j = idx >> 7, e = idx & 127;
        float ar = 0.f, ai = 0.f;
        for (int m = 0; m < E; ++m) {
            float tr = wt_re[j*E+m], ti = wt_im[j*E+m];
            float pr = wout_re[m*E+e], pi = wout_im[m*E+e];
            ar += tr*pr - ti*pi;
            ai += tr*pi + ti*pr;
        }
        Wfp_re[j*256 + e]       = bf16s(ar);
        Wfp_re[j*256 + 128 + e] = bf16s(-ai);
        Wfp_im[j*256 + e]       = bf16s(ai);
        Wfp_im[j*256 + 128 + e] = bf16s(ar);
    } else {
        // ---- fused bias: bf = wt @ bout + bt ----
        if (tid < E) {
            float br = bt_re[tid], bi = bt_im[tid];
            for (int m = 0; m < E; ++m) {
                float tr = wt_re[tid*E+m], ti = wt_im[tid*E+m];
                br += tr*bout_re[m] - ti*bout_im[m];
                bi += tr*bout_im[m] + ti*bout_re[m];
            }
            bf_re[tid] = br; bf_im[tid] = bi;
        }
    }
}

// ---------------------------------------------------------------------------
// Kernel 3: MFMA flash attention with LDS-shared K/V (round-6 verified).
// The 4 components (kf0,kf1,vr,vi -- identical across waves) are staged ONCE
// per block: wave w issues one global_load_lds for component w; LDS holds
// lane l's data at l*16, read back at l*16 -> bit-identical fragments.
// Double-buffered 8KB LDS, one __syncthreads per tile. Loads/block-iter: 4.
// ---------------------------------------------------------------------------
__global__ __launch_bounds__(256, 2) void attn_mfma_kernel(
    const short* __restrict__ Qpk, const short* __restrict__ Kpk,
    const short* __restrict__ Vtre, const short* __restrict__ Vtim,
    short* __restrict__ Opk)
{
    __shared__ short lbuf[2][4][512];   // [parity][component][1KB]

    int id   = blockIdx.x;
    int bh   = id & 63;
    int q0   = (id >> 6) * 128;
    int tid  = threadIdx.x;
    int wave = tid >> 6;
    int lane = tid & 63;
    int col  = lane & 15;
    int quad = lane >> 4;

    long kq_base = (long)bh * T * 32;
    int qbase = q0 + wave * 32;

    short8 qfA = *(const short8*)&Qpk[kq_base + (long)(qbase + col)*32 + quad*8];
    short8 qfB = *(const short8*)&Qpk[kq_base + (long)(qbase + 16 + col)*32 + quad*8];

    // this wave's staging component: 0=kf0, 1=kf1, 2=vr, 3=vi
    const short* gsrc;
    int gstep;
    if (wave == 0)      { gsrc = &Kpk[kq_base + col*32 + quad*8];              gstep = 1024; }
    else if (wave == 1) { gsrc = &Kpk[kq_base + 512 + col*32 + quad*8];        gstep = 1024; }
    else if (wave == 2) { gsrc = &Vtre[(long)bh*DH*T + (long)col*T + quad*8];  gstep = 32; }
    else                { gsrc = &Vtim[(long)bh*DH*T + (long)col*T + quad*8];  gstep = 32; }

    short8 ones;
    #pragma unroll
    for (int i = 0; i < 8; ++i) ones[i] = (short)0x3F80;   // bf16 1.0

    f32x4 oAr = {0,0,0,0}, oAi = {0,0,0,0}, lA = {0,0,0,0};
    f32x4 oBr = {0,0,0,0}, oBi = {0,0,0,0}, lB = {0,0,0,0};
    const f32x4 zero = {0.f,0.f,0.f,0.f};

    // prologue: stage tile 0 into parity 0
    stage16(gsrc, &lbuf[0][wave][0]);
    gsrc += gstep;
    __syncthreads();                    // tile 0 in LDS (vmcnt drained)

    for (int i = 0; i < 32; ++i) {
        int p = i & 1;
        // stage tile i+1 into the other buffer (overwrites tile i-1, whose
        // reads completed before the previous barrier). Tile-32 over-read
        // lands in LDS unused -- global side stays inside the workspace.
        stage16(gsrc, &lbuf[p^1][wave][0]);
        gsrc += gstep;

        // fragments from LDS (bit-identical to the original global loads)
        short8 kf0 = *(const short8*)&lbuf[p][0][lane*8];
        short8 kf1 = *(const short8*)&lbuf[p][1][lane*8];
        short8 vr  = *(const short8*)&lbuf[p][2][lane*8];
        short8 vi  = *(const short8*)&lbuf[p][3][lane*8];

        __builtin_amdgcn_s_setprio(1);
        f32x4 sA0 = __builtin_amdgcn_mfma_f32_16x16x32_bf16(kf0, qfA, zero, 0, 0, 0);
        f32x4 sA1 = __builtin_amdgcn_mfma_f32_16x16x32_bf16(kf1, qfA, zero, 0, 0, 0);
        f32x4 sB0 = __builtin_amdgcn_mfma_f32_16x16x32_bf16(kf0, qfB, zero, 0, 0, 0);
        f32x4 sB1 = __builtin_amdgcn_mfma_f32_16x16x32_bf16(kf1, qfB, zero, 0, 0, 0);
        __builtin_amdgcn_s_setprio(0);

        short8 pfA, pfB;
        {
            __hip_bfloat162* pa = (__hip_bfloat162*)&pfA;
            pa[0] = pk2(fexp2(sA0[0]), fexp2(sA0[1]));
            pa[1] = pk2(fexp2(sA0[2]), fexp2(sA0[3]));
            pa[2] = pk2(fexp2(sA1[0]), fexp2(sA1[1]));
            pa[3] = pk2(fexp2(sA1[2]), fexp2(sA1[3]));
            __hip_bfloat162* pb = (__hip_bfloat162*)&pfB;
            pb[0] = pk2(fexp2(sB0[0]), fexp2(sB0[1]));
            pb[1] = pk2(fexp2(sB0[2]), fexp2(sB0[3]));
            pb[2] = pk2(fexp2(sB1[0]), fexp2(sB1[1]));
            pb[3] = pk2(fexp2(sB1[2]), fexp2(sB1[3]));
        }

        __builtin_amdgcn_s_setprio(1);
        oAr = __builtin_amdgcn_mfma_f32_16x16x32_bf16(vr, pfA, oAr, 0, 0, 0);
        oAi = __builtin_amdgcn_mfma_f32_16x16x32_bf16(vi, pfA, oAi, 0, 0, 0);
        lA  = __builtin_amdgcn_mfma_f32_16x16x32_bf16(ones, pfA, lA, 0, 0, 0);
        oBr = __builtin_amdgcn_mfma_f32_16x16x32_bf16(vr, pfB, oBr, 0, 0, 0);
        oBi = __builtin_amdgcn_mfma_f32_16x16x32_bf16(vi, pfB, oBi, 0, 0, 0);
        lB  = __builtin_amdgcn_mfma_f32_16x16x32_bf16(ones, pfB, lB, 0, 0, 0);
        __builtin_amdgcn_s_setprio(0);

        __syncthreads();   // drains this iter's stage; syncs buf reads
    }

    int b = bh >> 3, h = bh & 7;
    float invA = 1.0f / lA[0];
    float invB = 1.0f / lB[0];

    long orowA = ((long)(b*T + qbase + col))*256 + h*16 + quad*4;
    {
        short4s pr, pi_;
        __hip_bfloat162* a = (__hip_bfloat162*)&pr;
        a[0] = pk2(oAr[0]*invA, oAr[1]*invA);
        a[1] = pk2(oAr[2]*invA, oAr[3]*invA);
        __hip_bfloat162* c = (__hip_bfloat162*)&pi_;
        c[0] = pk2(oAi[0]*invA, oAi[1]*invA);
        c[1] = pk2(oAi[2]*invA, oAi[3]*invA);
        *(short4s*)&Opk[orowA]       = pr;
        *(short4s*)&Opk[orowA + 128] = pi_;
    }
    long orowB = orowA + 16L*256;
    {
        short4s pr, pi_;
        __hip_bfloat162* a = (__hip_bfloat162*)&pr;
        a[0] = pk2(oBr[0]*invB, oBr[1]*invB);
        a[1] = pk2(oBr[2]*invB, oBr[3]*invB);
        __hip_bfloat162* c = (__hip_bfloat162*)&pi_;
        c[0] = pk2(oBi[0]*invB, oBi[1]*invB);
        c[1] = pk2(oBi[2]*invB, oBi[3]*invB);
        *(short4s*)&Opk[orowB]       = pr;
        *(short4s*)&Opk[orowB + 128] = pi_;
    }
}

// ---------------------------------------------------------------------------
// Kernel 4: MFMA output projection (round-6 verified version, grid 512).
// ---------------------------------------------------------------------------
__global__ __launch_bounds__(256) void outproj_mfma_kernel(
    const short* __restrict__ Opk,
    const short* __restrict__ Wfp_re, const short* __restrict__ Wfp_im,
    const float* __restrict__ bf_re, const float* __restrict__ bf_im,
    float* __restrict__ out)
{
    int tid  = threadIdx.x;
    int wave = tid >> 6, lane = tid & 63;
    int col  = lane & 15, quad = lane >> 4;
    int ttile = blockIdx.x;            // [0,512)
    int b  = ttile >> 6;
    int tb = (ttile & 63) * 16 + col;
    long trow = (long)b*T + tb;

    short8 xf[8];
    #pragma unroll
    for (int kt = 0; kt < 8; ++kt)
        xf[kt] = *(const short8*)&Opk[trow*256 + kt*32 + quad*8];

    const f32x4 zero = {0.f,0.f,0.f,0.f};
    #pragma unroll
    for (int ni = 0; ni < 4; ++ni) {
        int nt = wave * 4 + ni;            // [0,16)
        int is_im = nt >= 8;
        int jt = is_im ? nt - 8 : nt;      // [0,8)
        const short* Wsel = is_im ? Wfp_im : Wfp_re;
        const short* wrow = &Wsel[(jt*16 + col)*256 + quad*8];
        f32x4 acc = zero;
        #pragma unroll
        for (int kt = 0; kt < 8; ++kt) {
            short8 af = *(const short8*)(wrow + kt*32);
            acc = __builtin_amdgcn_mfma_f32_16x16x32_bf16(af, xf[kt], acc, 0, 0, 0);
        }
        const float* bias = is_im ? bf_im : bf_re;
        long part = is_im ? (long)B*E*T : 0;
        #pragma unroll
        for (int r = 0; r < 4; ++r) {
            int j = jt*16 + quad*4 + r;
            out[part + ((long)(b*E + j))*T + tb] = acc[r] + bias[j];
        }
    }
}

// ---------------------------------------------------------------------------
extern "C" void kernel_launch(void* const* d_in, const int* in_sizes, int n_in,
                              void* d_out, int out_size, void* d_ws, size_t ws_size,
                              hipStream_t stream)
{
    const float* x_re    = (const float*)d_in[0];
    const float* x_im    = (const float*)d_in[1];
    const float* win_re  = (const float*)d_in[2];
    const float* win_im  = (const float*)d_in[3];
    const float* bin_re  = (const float*)d_in[4];
    const float* bin_im  = (const float*)d_in[5];
    const float* wout_re = (const float*)d_in[6];
    const float* wout_im = (const float*)d_in[7];
    const float* bout_re = (const float*)d_in[8];
    const float* bout_im = (const float*)d_in[9];
    const float* wt_re   = (const float*)d_in[10];
    const float* wt_im   = (const float*)d_in[11];
    const float* bt_re   = (const float*)d_in[12];
    const float* bt_im   = (const float*)d_in[13];
    float* out = (float*)d_out;

    // workspace layout (shorts/floats)
    short* Qpk  = (short*)d_ws;                       // 64*1024*32 = 2M shorts
    short* Kpk  = Qpk + (long)B*H*T*32;
    short* Vtre = Kpk + (long)B*H*T*32;               // 64*16*1024 = 1M shorts
    short* Vtim = Vtre + (long)B*H*DH*T;
    short* Opk  = Vtim + (long)B*H*DH*T;              // 8*1024*256 = 2M shorts
    short* Wp_re  = Opk + (long)B*T*256;
    short* Wp_im  = Wp_re + E3*256;
    short* Wfp_re = Wp_im + E3*256;
    short* Wfp_im = Wfp_re + E*256;
    float* bf_re  = (float*)(Wfp_im + E*256);
    float* bf_im  = bf_re + E;

    pack_win_kernel<<<dim3(E3*E/256), dim3(256), 0, stream>>>(
        win_re, win_im, Wp_re, Wp_im);

    qkv_fuse_kernel<<<dim3(577), dim3(256), 0, stream>>>(
        x_re, x_im, Wp_re, Wp_im, bin_re, bin_im,
        wout_re, wout_im, bout_re, bout_im,
        wt_re, wt_im, bt_re, bt_im,
        Qpk, Kpk, Vtre, Vtim,
        Wfp_re, Wfp_im, bf_re, bf_im);

    attn_mfma_kernel<<<dim3(8 * 64), dim3(256), 0, stream>>>(
        Qpk, Kpk, Vtre, Vtim, Opk);

    outproj_mfma_kernel<<<dim3(512), dim3(256), 0, stream>>>(
        Opk, Wfp_re, Wfp_im, bf_re, bf_im, out);
}

// Round 9
// 135.687 us; speedup vs baseline: 1.0674x; 1.0149x over previous
//
#include <hip/hip_runtime.h>
#include <hip/hip_bf16.h>

#define B 8
#define T 1024
#define E 128
#define H 8
#define DH 16
#define E3 384

typedef __attribute__((ext_vector_type(8))) short short8;
typedef __attribute__((ext_vector_type(4))) short short4s;
typedef __attribute__((ext_vector_type(4))) float f32x4;

// fp32 -> bf16 (round-to-nearest-even), bit pattern in a short
static __device__ inline short bf16s(float x) {
    union { float f; unsigned u; } v; v.f = x;
    unsigned r = v.u + 0x7fffu + ((v.u >> 16) & 1u);
    return (short)(r >> 16);
}

// exp2 via the HW transcendental (1 inst)
#if __has_builtin(__builtin_amdgcn_exp2f)
static __device__ inline float fexp2(float x) { return __builtin_amdgcn_exp2f(x); }
#else
static __device__ inline float fexp2(float x) { return __builtin_exp2f(x); }
#endif

// pack two fp32 into bf16x2 via v_cvt_pk_bf16_f32
static __device__ inline __hip_bfloat162 pk2(float a, float b) {
    float2 t; t.x = a; t.y = b;
    return __float22bfloat162_rn(t);
}

// async global->LDS, 16B per lane: LDS gets lane l's data at base + l*16
static __device__ inline void stage16(const void* g, void* l) {
    __builtin_amdgcn_global_load_lds(
        (const __attribute__((address_space(1))) void*)g,
        (__attribute__((address_space(3))) void*)l,
        16, 0, 0);
}

#define QSCALE 0.36067376022224085f   /* 0.25 * log2(e) */

// ---------------------------------------------------------------------------
// Kernel 1: pack win into bf16 K=256 complex-packed layout (precedes qkv).
// ---------------------------------------------------------------------------
__global__ void pack_win_kernel(
    const float* __restrict__ win_re, const float* __restrict__ win_im,
    short* __restrict__ Wp_re, short* __restrict__ Wp_im)
{
    int idx = blockIdx.x * 256 + threadIdx.x;   // [0, 384*128)
    int j = idx >> 7, e = idx & 127;
    float wr = win_re[idx], wi = win_im[idx];
    Wp_re[j*256 + e]       = bf16s(wr);
    Wp_re[j*256 + 128 + e] = bf16s(-wi);
    Wp_im[j*256 + e]       = bf16s(wi);
    Wp_im[j*256 + 128 + e] = bf16s(wr);
}

// ---------------------------------------------------------------------------
// Kernel 2: QKV projection, register-blocked over t + piggy-backed fuse
// (round-8 verified: W traffic /4, load:MFMA ratio /4).
//   blocks [0,512):   qkv (jg = bid&3, ttile = bid>>2)
//   blocks [512,576): Wfp fuse (idx = (bid-512)*256 + tid)
//   block  576:       fused bias (threads 0..127)
// ---------------------------------------------------------------------------
__global__ __launch_bounds__(256, 2) void qkv_fuse_kernel(
    const float* __restrict__ x_re, const float* __restrict__ x_im,
    const short* __restrict__ Wp_re, const short* __restrict__ Wp_im,
    const float* __restrict__ bin_re, const float* __restrict__ bin_im,
    const float* __restrict__ wout_re, const float* __restrict__ wout_im,
    const float* __restrict__ bout_re, const float* __restrict__ bout_im,
    const float* __restrict__ wt_re,   const float* __restrict__ wt_im,
    const float* __restrict__ bt_re,   const float* __restrict__ bt_im,
    short* __restrict__ Qpk, short* __restrict__ Kpk,
    short* __restrict__ Vtre, short* __restrict__ Vtim,
    short* __restrict__ Wfp_re, short* __restrict__ Wfp_im,
    float* __restrict__ bf_re, float* __restrict__ bf_im)
{
    __shared__ short8 xsh[4][8][64];   // 32 KB: [tsub][kt][lane]

    int bid = blockIdx.x;
    int tid = threadIdx.x;

    if (bid < 512) {
        // ---- qkv ----
        int wave = tid >> 6, lane = tid & 63;
        int col  = lane & 15, quad = lane >> 4;
        int jg    = bid & 3;           // j-group: 6 j-tiles
        int ttile = bid >> 2;          // [0,128): 64-t tile
        int b  = ttile >> 4;
        int t0 = (ttile & 15) * 64;

        // wave w builds t-subtile w's 8 kt-fragments, shares via LDS
        {
            int tglob = t0 + wave*16 + col;
            #pragma unroll
            for (int kt = 0; kt < 8; ++kt) {
                const float* xs = (kt < 4) ? x_re : x_im;
                const float* p = &xs[((long)(b*E + (kt & 3)*32 + quad*8))*T + tglob];
                float v0 = p[0], v1 = p[(long)T], v2 = p[2L*T], v3 = p[3L*T];
                float v4 = p[4L*T], v5 = p[5L*T], v6 = p[6L*T], v7 = p[7L*T];
                short8 xv;
                __hip_bfloat162* xp = (__hip_bfloat162*)&xv;
                xp[0] = pk2(v0, v1); xp[1] = pk2(v2, v3);
                xp[2] = pk2(v4, v5); xp[3] = pk2(v6, v7);
                xsh[wave][kt][lane] = xv;
            }
        }
        __syncthreads();

        // all 4 t-subtiles' fragments into registers (static indexing)
        short8 xr[4][8];
        #pragma unroll
        for (int ts = 0; ts < 4; ++ts)
            #pragma unroll
            for (int kt = 0; kt < 8; ++kt)
                xr[ts][kt] = xsh[ts][kt][lane];

        const f32x4 zero = {0.f,0.f,0.f,0.f};

        // 12 j-units (6 j-tiles x 2 halves) / 4 waves = 3 per wave
        for (int ui = 0; ui < 3; ++ui) {
            int idx  = wave * 3 + ui;          // [0,12)
            int half = idx >= 6;
            int u    = half ? idx - 6 : idx;
            int jt   = jg * 6 + u;             // [0,24): which*8 + h
            const short* Wsel = half ? Wp_im : Wp_re;
            const float* bias = half ? bin_im : bin_re;
            const short* wrow = &Wsel[(jt*16 + col)*256 + quad*8];

            f32x4 acc[4] = {zero, zero, zero, zero};
            #pragma unroll
            for (int kt = 0; kt < 8; ++kt) {
                short8 af = *(const short8*)(wrow + kt*32);
                #pragma unroll
                for (int ts = 0; ts < 4; ++ts)
                    acc[ts] = __builtin_amdgcn_mfma_f32_16x16x32_bf16(af, xr[ts][kt], acc[ts], 0, 0, 0);
            }

            int which = jt >> 3;               // 0 q, 1 k, 2 v
            int h = jt & 7;
            float scale = (which == 0) ? QSCALE : 1.0f;
            long bh = b*H + h;

            #pragma unroll
            for (int ts = 0; ts < 4; ++ts) {
                int tb = t0 + ts*16 + col;
                f32x4 res;
                #pragma unroll
                for (int r = 0; r < 4; ++r) {
                    int jgl = which*128 + h*16 + quad*4 + r;
                    res[r] = (acc[ts][r] + bias[jgl]) * scale;
                }
                if (which == 2) {
                    // V transposed + pi-interleaved: Vt[bh][dh][blk*32 + pos]
                    short* vt = half ? Vtim : Vtre;
                    int tloc = tb & 31, tblk = tb & ~31;
                    int u2 = tloc & 15;
                    int kk = (u2 >> 2)*8 + (u2 & 3) + ((tloc >= 16) ? 4 : 0);
                    #pragma unroll
                    for (int r = 0; r < 4; ++r)
                        vt[(bh*DH + quad*4 + r)*T + tblk + kk] = bf16s(res[r]);
                } else {
                    short* qk = (which == 0) ? Qpk : Kpk;
                    short4s pk;
                    __hip_bfloat162* pp = (__hip_bfloat162*)&pk;
                    pp[0] = pk2(res[0], res[1]);
                    pp[1] = pk2(res[2], res[3]);
                    *(short4s*)&qk[(bh*T + tb)*32 + half*16 + quad*4] = pk;
                }
            }
        }
    } else if (bid < 576) {
        // ---- fuse output linears: wf = wt @ wout (complex) ----
        int idx = (bid - 512) * 256 + tid;        // [0, E*E)
        int j = idx >> 7, e = idx & 127;
        float ar = 0.f, ai = 0.f;
        for (int m = 0; m < E; ++m) {
            float tr = wt_re[j*E+m], ti = wt_im[j*E+m];
            float pr = wout_re[m*E+e], pi = wout_im[m*E+e];
            ar += tr*pr - ti*pi;
            ai += tr*pi + ti*pr;
        }
        Wfp_re[j*256 + e]       = bf16s(ar);
        Wfp_re[j*256 + 128 + e] = bf16s(-ai);
        Wfp_im[j*256 + e]       = bf16s(ai);
        Wfp_im[j*256 + 128 + e] = bf16s(ar);
    } else {
        // ---- fused bias: bf = wt @ bout + bt ----
        if (tid < E) {
            float br = bt_re[tid], bi = bt_im[tid];
            for (int m = 0; m < E; ++m) {
                float tr = wt_re[tid*E+m], ti = wt_im[tid*E+m];
                br += tr*bout_re[m] - ti*bout_im[m];
                bi += tr*bout_im[m] + ti*bout_re[m];
            }
            bf_re[tid] = br; bf_im[tid] = bi;
        }
    }
}

// ---------------------------------------------------------------------------
// Kernel 3: MFMA flash attention, LDS-shared K/V + counted-vmcnt pipeline.
// Round-9 change: __syncthreads emitted s_waitcnt vmcnt(0) -> every iter
// drained the stage it had JUST issued (full L2 latency exposed, 32x).
// T3/T4 fix: 3 buffers, stage tile i+2 at iter top, end iter with inline
// s_waitcnt vmcnt(1) (waits only the OLDER stage, tile i+1; the new one
// stays in flight) + raw s_barrier + sched_barrier(0) (rule-#18 guard).
// Buffer reuse safe: stage(i+2) overwrites buf[(i-1)%3], whose ds_reads
// completed before the previous barrier. Tail over-reads (tiles 32,33)
// stay inside the workspace; values never consumed.
// ---------------------------------------------------------------------------
__global__ __launch_bounds__(256, 2) void attn_mfma_kernel(
    const short* __restrict__ Qpk, const short* __restrict__ Kpk,
    const short* __restrict__ Vtre, const short* __restrict__ Vtim,
    short* __restrict__ Opk)
{
    __shared__ short lbuf[3][4][512];   // 12KB: [buf][component][1KB]

    int id   = blockIdx.x;
    int bh   = id & 63;
    int q0   = (id >> 6) * 128;
    int tid  = threadIdx.x;
    int wave = tid >> 6;
    int lane = tid & 63;
    int col  = lane & 15;
    int quad = lane >> 4;

    long kq_base = (long)bh * T * 32;
    int qbase = q0 + wave * 32;

    short8 qfA = *(const short8*)&Qpk[kq_base + (long)(qbase + col)*32 + quad*8];
    short8 qfB = *(const short8*)&Qpk[kq_base + (long)(qbase + 16 + col)*32 + quad*8];

    // this wave's staging component: 0=kf0, 1=kf1, 2=vr, 3=vi
    const short* gsrc;
    int gstep;
    if (wave == 0)      { gsrc = &Kpk[kq_base + col*32 + quad*8];              gstep = 1024; }
    else if (wave == 1) { gsrc = &Kpk[kq_base + 512 + col*32 + quad*8];        gstep = 1024; }
    else if (wave == 2) { gsrc = &Vtre[(long)bh*DH*T + (long)col*T + quad*8];  gstep = 32; }
    else                { gsrc = &Vtim[(long)bh*DH*T + (long)col*T + quad*8];  gstep = 32; }

    short8 ones;
    #pragma unroll
    for (int i = 0; i < 8; ++i) ones[i] = (short)0x3F80;   // bf16 1.0

    f32x4 oAr = {0,0,0,0}, oAi = {0,0,0,0}, lA = {0,0,0,0};
    f32x4 oBr = {0,0,0,0}, oBi = {0,0,0,0}, lB = {0,0,0,0};
    const f32x4 zero = {0.f,0.f,0.f,0.f};

    // prologue: stage tiles 0 and 1 (distance-2 pipeline)
    stage16(gsrc, &lbuf[0][wave][0]); gsrc += gstep;
    stage16(gsrc, &lbuf[1][wave][0]); gsrc += gstep;
    asm volatile("s_waitcnt vmcnt(1)" ::: "memory");   // tile 0 landed
    __builtin_amdgcn_s_barrier();
    __builtin_amdgcn_sched_barrier(0);

    for (int i = 0; i < 32; ++i) {
        int cur = i % 3;
        int nxt = (i + 2) % 3;
        // stage tile i+2 (stays in flight across this iter's barrier)
        stage16(gsrc, &lbuf[nxt][wave][0]);
        gsrc += gstep;

        // fragments from LDS (bit-identical to the original global loads)
        short8 kf0 = *(const short8*)&lbuf[cur][0][lane*8];
        short8 kf1 = *(const short8*)&lbuf[cur][1][lane*8];
        short8 vr  = *(const short8*)&lbuf[cur][2][lane*8];
        short8 vi  = *(const short8*)&lbuf[cur][3][lane*8];

        __builtin_amdgcn_s_setprio(1);
        f32x4 sA0 = __builtin_amdgcn_mfma_f32_16x16x32_bf16(kf0, qfA, zero, 0, 0, 0);
        f32x4 sA1 = __builtin_amdgcn_mfma_f32_16x16x32_bf16(kf1, qfA, zero, 0, 0, 0);
        f32x4 sB0 = __builtin_amdgcn_mfma_f32_16x16x32_bf16(kf0, qfB, zero, 0, 0, 0);
        f32x4 sB1 = __builtin_amdgcn_mfma_f32_16x16x32_bf16(kf1, qfB, zero, 0, 0, 0);
        __builtin_amdgcn_s_setprio(0);

        short8 pfA, pfB;
        {
            __hip_bfloat162* pa = (__hip_bfloat162*)&pfA;
            pa[0] = pk2(fexp2(sA0[0]), fexp2(sA0[1]));
            pa[1] = pk2(fexp2(sA0[2]), fexp2(sA0[3]));
            pa[2] = pk2(fexp2(sA1[0]), fexp2(sA1[1]));
            pa[3] = pk2(fexp2(sA1[2]), fexp2(sA1[3]));
            __hip_bfloat162* pb = (__hip_bfloat162*)&pfB;
            pb[0] = pk2(fexp2(sB0[0]), fexp2(sB0[1]));
            pb[1] = pk2(fexp2(sB0[2]), fexp2(sB0[3]));
            pb[2] = pk2(fexp2(sB1[0]), fexp2(sB1[1]));
            pb[3] = pk2(fexp2(sB1[2]), fexp2(sB1[3]));
        }

        __builtin_amdgcn_s_setprio(1);
        oAr = __builtin_amdgcn_mfma_f32_16x16x32_bf16(vr, pfA, oAr, 0, 0, 0);
        oAi = __builtin_amdgcn_mfma_f32_16x16x32_bf16(vi, pfA, oAi, 0, 0, 0);
        lA  = __builtin_amdgcn_mfma_f32_16x16x32_bf16(ones, pfA, lA, 0, 0, 0);
        oBr = __builtin_amdgcn_mfma_f32_16x16x32_bf16(vr, pfB, oBr, 0, 0, 0);
        oBi = __builtin_amdgcn_mfma_f32_16x16x32_bf16(vi, pfB, oBi, 0, 0, 0);
        lB  = __builtin_amdgcn_mfma_f32_16x16x32_bf16(ones, pfB, lB, 0, 0, 0);
        __builtin_amdgcn_s_setprio(0);

        // wait only the OLDER stage (tile i+1); tile i+2 stays in flight
        asm volatile("s_waitcnt vmcnt(1)" ::: "memory");
        __builtin_amdgcn_s_barrier();
        __builtin_amdgcn_sched_barrier(0);
    }

    int b = bh >> 3, h = bh & 7;
    float invA = 1.0f / lA[0];
    float invB = 1.0f / lB[0];

    long orowA = ((long)(b*T + qbase + col))*256 + h*16 + quad*4;
    {
        short4s pr, pi_;
        __hip_bfloat162* a = (__hip_bfloat162*)&pr;
        a[0] = pk2(oAr[0]*invA, oAr[1]*invA);
        a[1] = pk2(oAr[2]*invA, oAr[3]*invA);
        __hip_bfloat162* c = (__hip_bfloat162*)&pi_;
        c[0] = pk2(oAi[0]*invA, oAi[1]*invA);
        c[1] = pk2(oAi[2]*invA, oAi[3]*invA);
        *(short4s*)&Opk[orowA]       = pr;
        *(short4s*)&Opk[orowA + 128] = pi_;
    }
    long orowB = orowA + 16L*256;
    {
        short4s pr, pi_;
        __hip_bfloat162* a = (__hip_bfloat162*)&pr;
        a[0] = pk2(oBr[0]*invB, oBr[1]*invB);
        a[1] = pk2(oBr[2]*invB, oBr[3]*invB);
        __hip_bfloat162* c = (__hip_bfloat162*)&pi_;
        c[0] = pk2(oBi[0]*invB, oBi[1]*invB);
        c[1] = pk2(oBi[2]*invB, oBi[3]*invB);
        *(short4s*)&Opk[orowB]       = pr;
        *(short4s*)&Opk[orowB + 128] = pi_;
    }
}

// ---------------------------------------------------------------------------
// Kernel 4: MFMA output projection (round-6 verified version, grid 512).
// ---------------------------------------------------------------------------
__global__ __launch_bounds__(256) void outproj_mfma_kernel(
    const short* __restrict__ Opk,
    const short* __restrict__ Wfp_re, const short* __restrict__ Wfp_im,
    const float* __restrict__ bf_re, const float* __restrict__ bf_im,
    float* __restrict__ out)
{
    int tid  = threadIdx.x;
    int wave = tid >> 6, lane = tid & 63;
    int col  = lane & 15, quad = lane >> 4;
    int ttile = blockIdx.x;            // [0,512)
    int b  = ttile >> 6;
    int tb = (ttile & 63) * 16 + col;
    long trow = (long)b*T + tb;

    short8 xf[8];
    #pragma unroll
    for (int kt = 0; kt < 8; ++kt)
        xf[kt] = *(const short8*)&Opk[trow*256 + kt*32 + quad*8];

    const f32x4 zero = {0.f,0.f,0.f,0.f};
    #pragma unroll
    for (int ni = 0; ni < 4; ++ni) {
        int nt = wave * 4 + ni;            // [0,16)
        int is_im = nt >= 8;
        int jt = is_im ? nt - 8 : nt;      // [0,8)
        const short* Wsel = is_im ? Wfp_im : Wfp_re;
        const short* wrow = &Wsel[(jt*16 + col)*256 + quad*8];
        f32x4 acc = zero;
        #pragma unroll
        for (int kt = 0; kt < 8; ++kt) {
            short8 af = *(const short8*)(wrow + kt*32);
            acc = __builtin_amdgcn_mfma_f32_16x16x32_bf16(af, xf[kt], acc, 0, 0, 0);
        }
        const float* bias = is_im ? bf_im : bf_re;
        long part = is_im ? (long)B*E*T : 0;
        #pragma unroll
        for (int r = 0; r < 4; ++r) {
            int j = jt*16 + quad*4 + r;
            out[part + ((long)(b*E + j))*T + tb] = acc[r] + bias[j];
        }
    }
}

// ---------------------------------------------------------------------------
extern "C" void kernel_launch(void* const* d_in, const int* in_sizes, int n_in,
                              void* d_out, int out_size, void* d_ws, size_t ws_size,
                              hipStream_t stream)
{
    const float* x_re    = (const float*)d_in[0];
    const float* x_im    = (const float*)d_in[1];
    const float* win_re  = (const float*)d_in[2];
    const float* win_im  = (const float*)d_in[3];
    const float* bin_re  = (const float*)d_in[4];
    const float* bin_im  = (const float*)d_in[5];
    const float* wout_re = (const float*)d_in[6];
    const float* wout_im = (const float*)d_in[7];
    const float* bout_re = (const float*)d_in[8];
    const float* bout_im = (const float*)d_in[9];
    const float* wt_re   = (const float*)d_in[10];
    const float* wt_im   = (const float*)d_in[11];
    const float* bt_re   = (const float*)d_in[12];
    const float* bt_im   = (const float*)d_in[13];
    float* out = (float*)d_out;

    // workspace layout (shorts/floats)
    short* Qpk  = (short*)d_ws;                       // 64*1024*32 = 2M shorts
    short* Kpk  = Qpk + (long)B*H*T*32;
    short* Vtre = Kpk + (long)B*H*T*32;               // 64*16*1024 = 1M shorts
    short* Vtim = Vtre + (long)B*H*DH*T;
    short* Opk  = Vtim + (long)B*H*DH*T;              // 8*1024*256 = 2M shorts
    short* Wp_re  = Opk + (long)B*T*256;
    short* Wp_im  = Wp_re + E3*256;
    short* Wfp_re = Wp_im + E3*256;
    short* Wfp_im = Wfp_re + E*256;
    float* bf_re  = (float*)(Wfp_im + E*256);
    float* bf_im  = bf_re + E;

    pack_win_kernel<<<dim3(E3*E/256), dim3(256), 0, stream>>>(
        win_re, win_im, Wp_re, Wp_im);

    qkv_fuse_kernel<<<dim3(577), dim3(256), 0, stream>>>(
        x_re, x_im, Wp_re, Wp_im, bin_re, bin_im,
        wout_re, wout_im, bout_re, bout_im,
        wt_re, wt_im, bt_re, bt_im,
        Qpk, Kpk, Vtre, Vtim,
        Wfp_re, Wfp_im, bf_re, bf_im);

    attn_mfma_kernel<<<dim3(8 * 64), dim3(256), 0, stream>>>(
        Qpk, Kpk, Vtre, Vtim, Opk);

    outproj_mfma_kernel<<<dim3(512), dim3(256), 0, stream>>>(
        Opk, Wfp_re, Wfp_im, bf_re, bf_im, out);
}

// Round 10
// 132.786 us; speedup vs baseline: 1.0907x; 1.0218x over previous
//
#include <hip/hip_runtime.h>
#include <hip/hip_bf16.h>

#define B 8
#define T 1024
#define E 128
#define H 8
#define DH 16
#define E3 384

typedef __attribute__((ext_vector_type(8))) short short8;
typedef __attribute__((ext_vector_type(4))) short short4s;
typedef __attribute__((ext_vector_type(4))) float f32x4;

// fp32 -> bf16 (round-to-nearest-even), bit pattern in a short
static __device__ inline short bf16s(float x) {
    union { float f; unsigned u; } v; v.f = x;
    unsigned r = v.u + 0x7fffu + ((v.u >> 16) & 1u);
    return (short)(r >> 16);
}

// exp2 via the HW transcendental (1 inst)
#if __has_builtin(__builtin_amdgcn_exp2f)
static __device__ inline float fexp2(float x) { return __builtin_amdgcn_exp2f(x); }
#else
static __device__ inline float fexp2(float x) { return __builtin_exp2f(x); }
#endif

// pack two fp32 into bf16x2 via v_cvt_pk_bf16_f32
static __device__ inline __hip_bfloat162 pk2(float a, float b) {
    float2 t; t.x = a; t.y = b;
    return __float22bfloat162_rn(t);
}

// async global->LDS, 16B per lane: LDS gets lane l's data at base + l*16
static __device__ inline void stage16(const void* g, void* l) {
    __builtin_amdgcn_global_load_lds(
        (const __attribute__((address_space(1))) void*)g,
        (__attribute__((address_space(3))) void*)l,
        16, 0, 0);
}

#define QSCALE 0.36067376022224085f   /* 0.25 * log2(e) */

// ---------------------------------------------------------------------------
// Kernel 1: pack win into bf16 K=256 complex-packed layout (precedes qkv).
// ---------------------------------------------------------------------------
__global__ void pack_win_kernel(
    const float* __restrict__ win_re, const float* __restrict__ win_im,
    short* __restrict__ Wp_re, short* __restrict__ Wp_im)
{
    int idx = blockIdx.x * 256 + threadIdx.x;   // [0, 384*128)
    int j = idx >> 7, e = idx & 127;
    float wr = win_re[idx], wi = win_im[idx];
    Wp_re[j*256 + e]       = bf16s(wr);
    Wp_re[j*256 + 128 + e] = bf16s(-wi);
    Wp_im[j*256 + e]       = bf16s(wi);
    Wp_im[j*256 + 128 + e] = bf16s(wr);
}

// ---------------------------------------------------------------------------
// Kernel 2: QKV projection, register-blocked over t + piggy-backed fuse
// (round-8 verified: W traffic /4, load:MFMA ratio /4).
//   blocks [0,512):   qkv (jg = bid&3, ttile = bid>>2)
//   blocks [512,576): Wfp fuse (idx = (bid-512)*256 + tid)
//   block  576:       fused bias (threads 0..127)
// ---------------------------------------------------------------------------
__global__ __launch_bounds__(256, 2) void qkv_fuse_kernel(
    const float* __restrict__ x_re, const float* __restrict__ x_im,
    const short* __restrict__ Wp_re, const short* __restrict__ Wp_im,
    const float* __restrict__ bin_re, const float* __restrict__ bin_im,
    const float* __restrict__ wout_re, const float* __restrict__ wout_im,
    const float* __restrict__ bout_re, const float* __restrict__ bout_im,
    const float* __restrict__ wt_re,   const float* __restrict__ wt_im,
    const float* __restrict__ bt_re,   const float* __restrict__ bt_im,
    short* __restrict__ Qpk, short* __restrict__ Kpk,
    short* __restrict__ Vtre, short* __restrict__ Vtim,
    short* __restrict__ Wfp_re, short* __restrict__ Wfp_im,
    float* __restrict__ bf_re, float* __restrict__ bf_im)
{
    __shared__ short8 xsh[4][8][64];   // 32 KB: [tsub][kt][lane]

    int bid = blockIdx.x;
    int tid = threadIdx.x;

    if (bid < 512) {
        // ---- qkv ----
        int wave = tid >> 6, lane = tid & 63;
        int col  = lane & 15, quad = lane >> 4;
        int jg    = bid & 3;           // j-group: 6 j-tiles
        int ttile = bid >> 2;          // [0,128): 64-t tile
        int b  = ttile >> 4;
        int t0 = (ttile & 15) * 64;

        // wave w builds t-subtile w's 8 kt-fragments, shares via LDS
        {
            int tglob = t0 + wave*16 + col;
            #pragma unroll
            for (int kt = 0; kt < 8; ++kt) {
                const float* xs = (kt < 4) ? x_re : x_im;
                const float* p = &xs[((long)(b*E + (kt & 3)*32 + quad*8))*T + tglob];
                float v0 = p[0], v1 = p[(long)T], v2 = p[2L*T], v3 = p[3L*T];
                float v4 = p[4L*T], v5 = p[5L*T], v6 = p[6L*T], v7 = p[7L*T];
                short8 xv;
                __hip_bfloat162* xp = (__hip_bfloat162*)&xv;
                xp[0] = pk2(v0, v1); xp[1] = pk2(v2, v3);
                xp[2] = pk2(v4, v5); xp[3] = pk2(v6, v7);
                xsh[wave][kt][lane] = xv;
            }
        }
        __syncthreads();

        // all 4 t-subtiles' fragments into registers (static indexing)
        short8 xr[4][8];
        #pragma unroll
        for (int ts = 0; ts < 4; ++ts)
            #pragma unroll
            for (int kt = 0; kt < 8; ++kt)
                xr[ts][kt] = xsh[ts][kt][lane];

        const f32x4 zero = {0.f,0.f,0.f,0.f};

        // 12 j-units (6 j-tiles x 2 halves) / 4 waves = 3 per wave
        for (int ui = 0; ui < 3; ++ui) {
            int idx  = wave * 3 + ui;          // [0,12)
            int half = idx >= 6;
            int u    = half ? idx - 6 : idx;
            int jt   = jg * 6 + u;             // [0,24): which*8 + h
            const short* Wsel = half ? Wp_im : Wp_re;
            const float* bias = half ? bin_im : bin_re;
            const short* wrow = &Wsel[(jt*16 + col)*256 + quad*8];

            f32x4 acc[4] = {zero, zero, zero, zero};
            #pragma unroll
            for (int kt = 0; kt < 8; ++kt) {
                short8 af = *(const short8*)(wrow + kt*32);
                #pragma unroll
                for (int ts = 0; ts < 4; ++ts)
                    acc[ts] = __builtin_amdgcn_mfma_f32_16x16x32_bf16(af, xr[ts][kt], acc[ts], 0, 0, 0);
            }

            int which = jt >> 3;               // 0 q, 1 k, 2 v
            int h = jt & 7;
            float scale = (which == 0) ? QSCALE : 1.0f;
            long bh = b*H + h;

            #pragma unroll
            for (int ts = 0; ts < 4; ++ts) {
                int tb = t0 + ts*16 + col;
                f32x4 res;
                #pragma unroll
                for (int r = 0; r < 4; ++r) {
                    int jgl = which*128 + h*16 + quad*4 + r;
                    res[r] = (acc[ts][r] + bias[jgl]) * scale;
                }
                if (which == 2) {
                    // V transposed + pi-interleaved: Vt[bh][dh][blk*32 + pos]
                    short* vt = half ? Vtim : Vtre;
                    int tloc = tb & 31, tblk = tb & ~31;
                    int u2 = tloc & 15;
                    int kk = (u2 >> 2)*8 + (u2 & 3) + ((tloc >= 16) ? 4 : 0);
                    #pragma unroll
                    for (int r = 0; r < 4; ++r)
                        vt[(bh*DH + quad*4 + r)*T + tblk + kk] = bf16s(res[r]);
                } else {
                    short* qk = (which == 0) ? Qpk : Kpk;
                    short4s pk;
                    __hip_bfloat162* pp = (__hip_bfloat162*)&pk;
                    pp[0] = pk2(res[0], res[1]);
                    pp[1] = pk2(res[2], res[3]);
                    *(short4s*)&qk[(bh*T + tb)*32 + half*16 + quad*4] = pk;
                }
            }
        }
    } else if (bid < 576) {
        // ---- fuse output linears: wf = wt @ wout (complex) ----
        int idx = (bid - 512) * 256 + tid;        // [0, E*E)
        int j = idx >> 7, e = idx & 127;
        float ar = 0.f, ai = 0.f;
        for (int m = 0; m < E; ++m) {
            float tr = wt_re[j*E+m], ti = wt_im[j*E+m];
            float pr = wout_re[m*E+e], pi = wout_im[m*E+e];
            ar += tr*pr - ti*pi;
            ai += tr*pi + ti*pr;
        }
        Wfp_re[j*256 + e]       = bf16s(ar);
        Wfp_re[j*256 + 128 + e] = bf16s(-ai);
        Wfp_im[j*256 + e]       = bf16s(ai);
        Wfp_im[j*256 + 128 + e] = bf16s(ar);
    } else {
        // ---- fused bias: bf = wt @ bout + bt ----
        if (tid < E) {
            float br = bt_re[tid], bi = bt_im[tid];
            for (int m = 0; m < E; ++m) {
                float tr = wt_re[tid*E+m], ti = wt_im[tid*E+m];
                br += tr*bout_re[m] - ti*bout_im[m];
                bi += tr*bout_im[m] + ti*bout_re[m];
            }
            bf_re[tid] = br; bf_im[tid] = bi;
        }
    }
}

// ---------------------------------------------------------------------------
// Kernel 3: MFMA flash attention, LDS-shared K/V, 2-tile barrier windows.
// Round-10 change: 6 buffers; per window stage tiles i+4,i+5, compute
// tiles i,i+1, end with s_waitcnt vmcnt(2) (tiles i+2,i+3 landed; newest
// two stay in flight) + raw s_barrier. Barrier count 32 -> 16. Buffer
// reuse safe: stage(i+4) overwrites buf[(i-2)%6], read-complete before
// the previous barrier. Tail over-reads stay inside the workspace; a
// final vmcnt(0) drain before the epilogue guarantees no LDS-DMA is
// outstanding at block exit (hazard present in rounds 8-9, now closed).
// ---------------------------------------------------------------------------
__global__ __launch_bounds__(256, 2) void attn_mfma_kernel(
    const short* __restrict__ Qpk, const short* __restrict__ Kpk,
    const short* __restrict__ Vtre, const short* __restrict__ Vtim,
    short* __restrict__ Opk)
{
    __shared__ short lbuf[6][4][512];   // 24KB: [buf][component][1KB]

    int id   = blockIdx.x;
    int bh   = id & 63;
    int q0   = (id >> 6) * 128;
    int tid  = threadIdx.x;
    int wave = tid >> 6;
    int lane = tid & 63;
    int col  = lane & 15;
    int quad = lane >> 4;

    long kq_base = (long)bh * T * 32;
    int qbase = q0 + wave * 32;

    short8 qfA = *(const short8*)&Qpk[kq_base + (long)(qbase + col)*32 + quad*8];
    short8 qfB = *(const short8*)&Qpk[kq_base + (long)(qbase + 16 + col)*32 + quad*8];

    // this wave's staging component: 0=kf0, 1=kf1, 2=vr, 3=vi
    const short* gsrc;
    int gstep;
    if (wave == 0)      { gsrc = &Kpk[kq_base + col*32 + quad*8];              gstep = 1024; }
    else if (wave == 1) { gsrc = &Kpk[kq_base + 512 + col*32 + quad*8];        gstep = 1024; }
    else if (wave == 2) { gsrc = &Vtre[(long)bh*DH*T + (long)col*T + quad*8];  gstep = 32; }
    else                { gsrc = &Vtim[(long)bh*DH*T + (long)col*T + quad*8];  gstep = 32; }

    short8 ones;
    #pragma unroll
    for (int i = 0; i < 8; ++i) ones[i] = (short)0x3F80;   // bf16 1.0

    f32x4 oAr = {0,0,0,0}, oAi = {0,0,0,0}, lA = {0,0,0,0};
    f32x4 oBr = {0,0,0,0}, oBi = {0,0,0,0}, lB = {0,0,0,0};
    const f32x4 zero = {0.f,0.f,0.f,0.f};

    // one K/V tile worth of compute from LDS buffer bi (runtime LDS index
    // is plain address arithmetic -- no register-array scratch issue)
    auto COMPUTE = [&](int bi) {
        short8 kf0 = *(const short8*)&lbuf[bi][0][lane*8];
        short8 kf1 = *(const short8*)&lbuf[bi][1][lane*8];
        short8 vr  = *(const short8*)&lbuf[bi][2][lane*8];
        short8 vi  = *(const short8*)&lbuf[bi][3][lane*8];

        __builtin_amdgcn_s_setprio(1);
        f32x4 sA0 = __builtin_amdgcn_mfma_f32_16x16x32_bf16(kf0, qfA, zero, 0, 0, 0);
        f32x4 sA1 = __builtin_amdgcn_mfma_f32_16x16x32_bf16(kf1, qfA, zero, 0, 0, 0);
        f32x4 sB0 = __builtin_amdgcn_mfma_f32_16x16x32_bf16(kf0, qfB, zero, 0, 0, 0);
        f32x4 sB1 = __builtin_amdgcn_mfma_f32_16x16x32_bf16(kf1, qfB, zero, 0, 0, 0);
        __builtin_amdgcn_s_setprio(0);

        short8 pfA, pfB;
        {
            __hip_bfloat162* pa = (__hip_bfloat162*)&pfA;
            pa[0] = pk2(fexp2(sA0[0]), fexp2(sA0[1]));
            pa[1] = pk2(fexp2(sA0[2]), fexp2(sA0[3]));
            pa[2] = pk2(fexp2(sA1[0]), fexp2(sA1[1]));
            pa[3] = pk2(fexp2(sA1[2]), fexp2(sA1[3]));
            __hip_bfloat162* pb = (__hip_bfloat162*)&pfB;
            pb[0] = pk2(fexp2(sB0[0]), fexp2(sB0[1]));
            pb[1] = pk2(fexp2(sB0[2]), fexp2(sB0[3]));
            pb[2] = pk2(fexp2(sB1[0]), fexp2(sB1[1]));
            pb[3] = pk2(fexp2(sB1[2]), fexp2(sB1[3]));
        }

        __builtin_amdgcn_s_setprio(1);
        oAr = __builtin_amdgcn_mfma_f32_16x16x32_bf16(vr, pfA, oAr, 0, 0, 0);
        oAi = __builtin_amdgcn_mfma_f32_16x16x32_bf16(vi, pfA, oAi, 0, 0, 0);
        lA  = __builtin_amdgcn_mfma_f32_16x16x32_bf16(ones, pfA, lA, 0, 0, 0);
        oBr = __builtin_amdgcn_mfma_f32_16x16x32_bf16(vr, pfB, oBr, 0, 0, 0);
        oBi = __builtin_amdgcn_mfma_f32_16x16x32_bf16(vi, pfB, oBi, 0, 0, 0);
        lB  = __builtin_amdgcn_mfma_f32_16x16x32_bf16(ones, pfB, lB, 0, 0, 0);
        __builtin_amdgcn_s_setprio(0);
    };

    // prologue: stage tiles 0..3 (distance-4 pipeline)
    stage16(gsrc, &lbuf[0][wave][0]); gsrc += gstep;
    stage16(gsrc, &lbuf[1][wave][0]); gsrc += gstep;
    stage16(gsrc, &lbuf[2][wave][0]); gsrc += gstep;
    stage16(gsrc, &lbuf[3][wave][0]); gsrc += gstep;
    asm volatile("s_waitcnt vmcnt(2)" ::: "memory");   // tiles 0,1 landed
    __builtin_amdgcn_s_barrier();
    __builtin_amdgcn_sched_barrier(0);

    for (int i = 0; i < 32; i += 2) {
        // stage tiles i+4, i+5 (stay in flight across this window's barrier)
        stage16(gsrc, &lbuf[(i+4)%6][wave][0]); gsrc += gstep;
        stage16(gsrc, &lbuf[(i+5)%6][wave][0]); gsrc += gstep;

        COMPUTE(i % 6);          // tile i
        COMPUTE((i+1) % 6);      // tile i+1

        // wait the OLDER two stages (tiles i+2,i+3); newest two in flight
        asm volatile("s_waitcnt vmcnt(2)" ::: "memory");
        __builtin_amdgcn_s_barrier();
        __builtin_amdgcn_sched_barrier(0);
    }

    // drain remaining LDS-DMA before epilogue/exit (no stray writes after
    // this block's LDS slot is reallocated)
    asm volatile("s_waitcnt vmcnt(0)" ::: "memory");

    int b = bh >> 3, h = bh & 7;
    float invA = 1.0f / lA[0];
    float invB = 1.0f / lB[0];

    long orowA = ((long)(b*T + qbase + col))*256 + h*16 + quad*4;
    {
        short4s pr, pi_;
        __hip_bfloat162* a = (__hip_bfloat162*)&pr;
        a[0] = pk2(oAr[0]*invA, oAr[1]*invA);
        a[1] = pk2(oAr[2]*invA, oAr[3]*invA);
        __hip_bfloat162* c = (__hip_bfloat162*)&pi_;
        c[0] = pk2(oAi[0]*invA, oAi[1]*invA);
        c[1] = pk2(oAi[2]*invA, oAi[3]*invA);
        *(short4s*)&Opk[orowA]       = pr;
        *(short4s*)&Opk[orowA + 128] = pi_;
    }
    long orowB = orowA + 16L*256;
    {
        short4s pr, pi_;
        __hip_bfloat162* a = (__hip_bfloat162*)&pr;
        a[0] = pk2(oBr[0]*invB, oBr[1]*invB);
        a[1] = pk2(oBr[2]*invB, oBr[3]*invB);
        __hip_bfloat162* c = (__hip_bfloat162*)&pi_;
        c[0] = pk2(oBi[0]*invB, oBi[1]*invB);
        c[1] = pk2(oBi[2]*invB, oBi[3]*invB);
        *(short4s*)&Opk[orowB]       = pr;
        *(short4s*)&Opk[orowB + 128] = pi_;
    }
}

// ---------------------------------------------------------------------------
// Kernel 4: MFMA output projection, register-blocked over t (mirror of the
// round-8 qkv fix). Old shape: every one of 512 blocks streamed the whole
// 128KB Wfp from L2 (64MB) at 1:1 load:MFMA. New: grid = 128 t-tiles (64t)
// x 4 j-groups; Opk fragments staged once per block via global_load_lds
// (pure copy -> per-lane global addr, LDS lane*16, bit-identical readback);
// each wave owns ONE j-unit whose 8 af loads feed 32 MFMAs.
// W traffic 64->16MB; load:MFMA 1:4. Store formulas unchanged.
// ---------------------------------------------------------------------------
__global__ __launch_bounds__(256, 2) void outproj_mfma_kernel(
    const short* __restrict__ Opk,
    const short* __restrict__ Wfp_re, const short* __restrict__ Wfp_im,
    const float* __restrict__ bf_re, const float* __restrict__ bf_im,
    float* __restrict__ out)
{
    __shared__ short8 osh[4][8][64];   // 32 KB: [tsub][kt][lane]

    int tid  = threadIdx.x;
    int wave = tid >> 6, lane = tid & 63;
    int col  = lane & 15, quad = lane >> 4;
    int jg    = blockIdx.x & 3;        // j-group: 4 j-units
    int ttile = blockIdx.x >> 2;       // [0,128): 64-t tile
    int b  = ttile >> 4;
    int t0 = (ttile & 15) * 64;

    // wave w stages t-subtile w's 8 kt-fragments (async copy, no convert)
    {
        long trow = (long)b*T + t0 + wave*16 + col;
        #pragma unroll
        for (int kt = 0; kt < 8; ++kt)
            stage16(&Opk[trow*256 + kt*32 + quad*8], &osh[wave][kt][0]);
    }
    __syncthreads();   // vmcnt(0) drain + barrier: all 32 stages landed

    short8 xr[4][8];
    #pragma unroll
    for (int ts = 0; ts < 4; ++ts)
        #pragma unroll
        for (int kt = 0; kt < 8; ++kt)
            xr[ts][kt] = osh[ts][kt][lane];

    const f32x4 zero = {0.f,0.f,0.f,0.f};

    int nt = jg*4 + wave;              // [0,16): this wave's j-unit
    int is_im = nt >= 8;
    int jt = is_im ? nt - 8 : nt;      // [0,8)
    const short* Wsel = is_im ? Wfp_im : Wfp_re;
    const short* wrow = &Wsel[(jt*16 + col)*256 + quad*8];

    f32x4 acc[4] = {zero, zero, zero, zero};
    #pragma unroll
    for (int kt = 0; kt < 8; ++kt) {
        short8 af = *(const short8*)(wrow + kt*32);
        #pragma unroll
        for (int ts = 0; ts < 4; ++ts)
            acc[ts] = __builtin_amdgcn_mfma_f32_16x16x32_bf16(af, xr[ts][kt], acc[ts], 0, 0, 0);
    }

    const float* bias = is_im ? bf_im : bf_re;
    long part = is_im ? (long)B*E*T : 0;
    #pragma unroll
    for (int ts = 0; ts < 4; ++ts) {
        int tb = t0 + ts*16 + col;
        #pragma unroll
        for (int r = 0; r < 4; ++r) {
            int j = jt*16 + quad*4 + r;
            out[part + ((long)(b*E + j))*T + tb] = acc[ts][r] + bias[j];
        }
    }
}

// ---------------------------------------------------------------------------
extern "C" void kernel_launch(void* const* d_in, const int* in_sizes, int n_in,
                              void* d_out, int out_size, void* d_ws, size_t ws_size,
                              hipStream_t stream)
{
    const float* x_re    = (const float*)d_in[0];
    const float* x_im    = (const float*)d_in[1];
    const float* win_re  = (const float*)d_in[2];
    const float* win_im  = (const float*)d_in[3];
    const float* bin_re  = (const float*)d_in[4];
    const float* bin_im  = (const float*)d_in[5];
    const float* wout_re = (const float*)d_in[6];
    const float* wout_im = (const float*)d_in[7];
    const float* bout_re = (const float*)d_in[8];
    const float* bout_im = (const float*)d_in[9];
    const float* wt_re   = (const float*)d_in[10];
    const float* wt_im   = (const float*)d_in[11];
    const float* bt_re   = (const float*)d_in[12];
    const float* bt_im   = (const float*)d_in[13];
    float* out = (float*)d_out;

    // workspace layout (shorts/floats)
    short* Qpk  = (short*)d_ws;                       // 64*1024*32 = 2M shorts
    short* Kpk  = Qpk + (long)B*H*T*32;
    short* Vtre = Kpk + (long)B*H*T*32;               // 64*16*1024 = 1M shorts
    short* Vtim = Vtre + (long)B*H*DH*T;
    short* Opk  = Vtim + (long)B*H*DH*T;              // 8*1024*256 = 2M shorts
    short* Wp_re  = Opk + (long)B*T*256;
    short* Wp_im  = Wp_re + E3*256;
    short* Wfp_re = Wp_im + E3*256;
    short* Wfp_im = Wfp_re + E*256;
    float* bf_re  = (float*)(Wfp_im + E*256);
    float* bf_im  = bf_re + E;

    pack_win_kernel<<<dim3(E3*E/256), dim3(256), 0, stream>>>(
        win_re, win_im, Wp_re, Wp_im);

    qkv_fuse_kernel<<<dim3(577), dim3(256), 0, stream>>>(
        x_re, x_im, Wp_re, Wp_im, bin_re, bin_im,
        wout_re, wout_im, bout_re, bout_im,
        wt_re, wt_im, bt_re, bt_im,
        Qpk, Kpk, Vtre, Vtim,
        Wfp_re, Wfp_im, bf_re, bf_im);

    attn_mfma_kernel<<<dim3(8 * 64), dim3(256), 0, stream>>>(
        Qpk, Kpk, Vtre, Vtim, Opk);

    outproj_mfma_kernel<<<dim3(512), dim3(256), 0, stream>>>(
        Opk, Wfp_re, Wfp_im, bf_re, bf_im, out);
}